// Round 1
// baseline (1820.780 us; speedup 1.0000x reference)
//
#include <hip/hip_runtime.h>
#include <hip/hip_bf16.h>
#include <math.h>

// ---------------------------------------------------------------------------
// ActorGNN: 4-layer GraphConv (gather -> scatter-add mean -> dense) + sigmoid
// N=100000, E=1600000, dims 64->64->64->64->1
// ---------------------------------------------------------------------------

__device__ __forceinline__ int load_idx(const void* ei, int is64, long long pos) {
    if (is64) return (int)((const long long*)ei)[pos];
    return ((const int*)ei)[pos];
}

// Detect whether edge_index is int64 or int32: if int64 (values < 2^31),
// every odd 32-bit word of the first 32 entries is zero.
__global__ void detect_idx_kernel(const int* __restrict__ ei, int* __restrict__ flag) {
    int allz = 1;
    for (int i = 0; i < 32; ++i)
        if (ei[2 * i + 1] != 0) allz = 0;
    *flag = allz;  // 1 => int64, 0 => int32
}

__global__ void deg_kernel(const void* __restrict__ ei, const int* __restrict__ flagp,
                           float* __restrict__ deg, int E) {
    int e = blockIdx.x * blockDim.x + threadIdx.x;
    if (e >= E) return;
    int is64 = *flagp;
    int dst = load_idx(ei, is64, (long long)E + e);
    atomicAdd(&deg[dst], 1.0f);
}

__global__ void deginv_kernel(float* __restrict__ deg, int N) {
    int n = blockIdx.x * blockDim.x + threadIdx.x;
    if (n < N) deg[n] = 1.0f / fmaxf(deg[n], 1.0f);
}

// One wave per edge: lane d handles feature dim d. Coalesced row read + atomics.
__global__ void scatter64_kernel(const float* __restrict__ h, const void* __restrict__ ei,
                                 const int* __restrict__ flagp, float* __restrict__ agg, int E) {
    long long tid = (long long)blockIdx.x * blockDim.x + threadIdx.x;
    long long ntot = (long long)E * 64;
    if (tid >= ntot) return;
    int e = (int)(tid >> 6);
    int d = (int)(tid & 63);
    int is64 = *flagp;
    int src = load_idx(ei, is64, e);
    int dst = load_idx(ei, is64, (long long)E + e);
    float v = h[(long long)src * 64 + d];
    atomicAdd(&agg[(long long)dst * 64 + d], v);
}

// out[n,:] = act(h[n,:] @ Ws + deginv[n] * agg[n,:] @ Wn + b)
// One wave per node; Ws/Wn staged in LDS. Safe when out aliases agg
// (each wave reads its full agg row before storing).
__global__ __launch_bounds__(256) void dense64_kernel(
    const float* __restrict__ h, const float* __restrict__ agg,
    const float* __restrict__ deginv, const float* __restrict__ Ws,
    const float* __restrict__ Wn, const float* __restrict__ b,
    float* __restrict__ out, int N, int do_relu) {
    __shared__ float sWs[64 * 64];
    __shared__ float sWn[64 * 64];
    for (int i = threadIdx.x; i < 64 * 64; i += 256) {
        sWs[i] = Ws[i];
        sWn[i] = Wn[i];
    }
    __syncthreads();
    int wave = threadIdx.x >> 6;
    int lane = threadIdx.x & 63;
    int n = blockIdx.x * 4 + wave;
    if (n >= N) return;
    const float* hrow = h + (long long)n * 64;
    const float* arow = agg + (long long)n * 64;
    float accs = 0.f, accn = 0.f;
#pragma unroll 8
    for (int k = 0; k < 64; ++k) {
        float hk = hrow[k];
        float ak = arow[k];
        accs = fmaf(hk, sWs[k * 64 + lane], accs);
        accn = fmaf(ak, sWn[k * 64 + lane], accn);
    }
    float v = accs + deginv[n] * accn + b[lane];
    if (do_relu) v = fmaxf(v, 0.f);
    out[(long long)n * 64 + lane] = v;
}

// Layer 4 pre-transform: s[n] = h[n,:]·Wself4, g[n] = h[n,:]·Wneigh4 (both 64->1)
__global__ __launch_bounds__(256) void layer4_pre_kernel(
    const float* __restrict__ h, const float* __restrict__ Ws,
    const float* __restrict__ Wn, float* __restrict__ s, float* __restrict__ g, int N) {
    int wave = threadIdx.x >> 6;
    int lane = threadIdx.x & 63;
    int n = blockIdx.x * 4 + wave;
    if (n >= N) return;
    float hv = h[(long long)n * 64 + lane];
    float vs = hv * Ws[lane];
    float vn = hv * Wn[lane];
#pragma unroll
    for (int off = 32; off > 0; off >>= 1) {
        vs += __shfl_down(vs, off, 64);
        vn += __shfl_down(vn, off, 64);
    }
    if (lane == 0) {
        s[n] = vs;
        g[n] = vn;
    }
}

__global__ void scatter1_kernel(const float* __restrict__ g, const void* __restrict__ ei,
                                const int* __restrict__ flagp, float* __restrict__ agg1, int E) {
    int e = blockIdx.x * blockDim.x + threadIdx.x;
    if (e >= E) return;
    int is64 = *flagp;
    int src = load_idx(ei, is64, e);
    int dst = load_idx(ei, is64, (long long)E + e);
    atomicAdd(&agg1[dst], g[src]);
}

__global__ void final_kernel(const float* __restrict__ s, const float* __restrict__ deginv,
                             const float* __restrict__ agg1, const float* __restrict__ b4,
                             float* __restrict__ out, int N) {
    int n = blockIdx.x * blockDim.x + threadIdx.x;
    if (n >= N) return;
    float z = s[n] + deginv[n] * agg1[n] + b4[0];
    out[n] = 1.0f / (1.0f + expf(-z));
}

static inline int cdiv(long long a, long long b) { return (int)((a + b - 1) / b); }

extern "C" void kernel_launch(void* const* d_in, const int* in_sizes, int n_in,
                              void* d_out, int out_size, void* d_ws, size_t ws_size,
                              hipStream_t stream) {
    const float* x   = (const float*)d_in[0];
    const void*  ei  = d_in[1];
    const float* Ws1 = (const float*)d_in[2];
    const float* Wn1 = (const float*)d_in[3];
    const float* b1  = (const float*)d_in[4];
    const float* Ws2 = (const float*)d_in[5];
    const float* Wn2 = (const float*)d_in[6];
    const float* b2  = (const float*)d_in[7];
    const float* Ws3 = (const float*)d_in[8];
    const float* Wn3 = (const float*)d_in[9];
    const float* b3  = (const float*)d_in[10];
    const float* Ws4 = (const float*)d_in[11];
    const float* Wn4 = (const float*)d_in[12];
    const float* b4  = (const float*)d_in[13];
    float* out = (float*)d_out;

    const int N = in_sizes[0] / 64;
    const int E = in_sizes[1] / 2;

    float* bufA   = (float*)d_ws;                    // N*64
    float* bufB   = bufA + (size_t)N * 64;           // N*64
    float* deginv = bufB + (size_t)N * 64;           // N
    float* sbuf   = deginv + N;                      // N
    float* gbuf   = sbuf + N;                        // N
    float* agg1   = gbuf + N;                        // N
    int*   flag   = (int*)(agg1 + N);                // 1

    const int BT = 256;
    const int gridN   = cdiv(N, BT);
    const int gridE   = cdiv(E, BT);
    const int gridE64 = cdiv((long long)E * 64, BT);
    const int gridNd  = cdiv(N, 4);  // wave-per-node kernels (4 waves/block)

    // edge-index width detection
    detect_idx_kernel<<<1, 1, 0, stream>>>((const int*)ei, flag);

    // degree -> deg_inv (layer-invariant)
    hipMemsetAsync(deginv, 0, (size_t)N * sizeof(float), stream);
    deg_kernel<<<gridE, BT, 0, stream>>>(ei, flag, deginv, E);
    deginv_kernel<<<gridN, BT, 0, stream>>>(deginv, N);

    // ---- layer 1: x -> bufA ----
    hipMemsetAsync(bufA, 0, (size_t)N * 64 * sizeof(float), stream);
    scatter64_kernel<<<gridE64, BT, 0, stream>>>(x, ei, flag, bufA, E);
    dense64_kernel<<<gridNd, BT, 0, stream>>>(x, bufA, deginv, Ws1, Wn1, b1, bufA, N, 1);

    // ---- layer 2: bufA -> bufB ----
    hipMemsetAsync(bufB, 0, (size_t)N * 64 * sizeof(float), stream);
    scatter64_kernel<<<gridE64, BT, 0, stream>>>(bufA, ei, flag, bufB, E);
    dense64_kernel<<<gridNd, BT, 0, stream>>>(bufA, bufB, deginv, Ws2, Wn2, b2, bufB, N, 1);

    // ---- layer 3: bufB -> bufA ----
    hipMemsetAsync(bufA, 0, (size_t)N * 64 * sizeof(float), stream);
    scatter64_kernel<<<gridE64, BT, 0, stream>>>(bufB, ei, flag, bufA, E);
    dense64_kernel<<<gridNd, BT, 0, stream>>>(bufB, bufA, deginv, Ws3, Wn3, b3, bufA, N, 1);

    // ---- layer 4 (64->1): pre-transform, scalar scatter, sigmoid ----
    layer4_pre_kernel<<<gridNd, BT, 0, stream>>>(bufA, Ws4, Wn4, sbuf, gbuf, N);
    hipMemsetAsync(agg1, 0, (size_t)N * sizeof(float), stream);
    scatter1_kernel<<<gridE, BT, 0, stream>>>(gbuf, ei, flag, agg1, E);
    final_kernel<<<gridN, BT, 0, stream>>>(sbuf, deginv, agg1, b4, out, N);
}

// Round 2
// 902.531 us; speedup vs baseline: 2.0174x; 2.0174x over previous
//
#include <hip/hip_runtime.h>
#include <hip/hip_bf16.h>
#include <math.h>

// ---------------------------------------------------------------------------
// ActorGNN: 4-layer GraphConv. R2: replace float scatter-atomics (3x380us,
// atomic write-through wall) with once-per-call CSR build + wave-per-node
// gather (zero float atomics).
// ---------------------------------------------------------------------------

__device__ __forceinline__ int load_idx(const void* ei, int is64, long long pos) {
    if (is64) return (int)((const long long*)ei)[pos];
    return ((const int*)ei)[pos];
}

// int64 vs int32 edge_index detection (int64 values < 2^31 => odd words zero)
__global__ void detect_idx_kernel(const int* __restrict__ ei, int* __restrict__ flag) {
    int allz = 1;
    for (int i = 0; i < 32; ++i)
        if (ei[2 * i + 1] != 0) allz = 0;
    *flag = allz;
}

__global__ void zero_int_kernel(int* __restrict__ p, int n) {
    int i = blockIdx.x * blockDim.x + threadIdx.x;
    if (i < n) p[i] = 0;
}

__global__ void hist_kernel(const void* __restrict__ ei, const int* __restrict__ flagp,
                            int* __restrict__ degi, int E) {
    int e = blockIdx.x * blockDim.x + threadIdx.x;
    if (e >= E) return;
    int is64 = *flagp;
    int dst = load_idx(ei, is64, (long long)E + e);
    atomicAdd(&degi[dst], 1);
}

// exclusive scan over degi -> off, 1024 elems/block, block sums -> bsum
__global__ __launch_bounds__(256) void scanA_kernel(const int* __restrict__ degi,
                                                    int* __restrict__ off,
                                                    int* __restrict__ bsum, int N) {
    __shared__ int lds[256];
    int t = threadIdx.x;
    int base = blockIdx.x * 1024 + t * 4;
    int d[4];
#pragma unroll
    for (int i = 0; i < 4; ++i) d[i] = (base + i < N) ? degi[base + i] : 0;
    int s = d[0] + d[1] + d[2] + d[3];
    lds[t] = s;
    __syncthreads();
    for (int o = 1; o < 256; o <<= 1) {
        int v = (t >= o) ? lds[t - o] : 0;
        __syncthreads();
        lds[t] += v;
        __syncthreads();
    }
    int excl = lds[t] - s;
    if (t == 255) bsum[blockIdx.x] = lds[255];
    int p = excl;
#pragma unroll
    for (int i = 0; i < 4; ++i) {
        if (base + i < N) off[base + i] = p;
        p += d[i];
    }
}

// exclusive scan of block sums in place (B <= 1024)
__global__ __launch_bounds__(1024) void scanB_kernel(int* __restrict__ bsum, int B) {
    __shared__ int lds[1024];
    int t = threadIdx.x;
    int s = (t < B) ? bsum[t] : 0;
    lds[t] = s;
    __syncthreads();
    for (int o = 1; o < 1024; o <<= 1) {
        int v = (t >= o) ? lds[t - o] : 0;
        __syncthreads();
        lds[t] += v;
        __syncthreads();
    }
    if (t < B) bsum[t] = lds[t] - s;
}

__global__ void scanC_kernel(int* __restrict__ off, const int* __restrict__ bsum, int N) {
    int i = blockIdx.x * blockDim.x + threadIdx.x;
    if (i < N) off[i] += bsum[i >> 10];
}

__global__ void copy_int_kernel(int* __restrict__ dstp, const int* __restrict__ srcp, int n) {
    int i = blockIdx.x * blockDim.x + threadIdx.x;
    if (i < n) dstp[i] = srcp[i];
}

// fill CSR buckets; afterwards cur[n] == off[n] + deg[n] (used as `end`)
__global__ void fill_kernel(const void* __restrict__ ei, const int* __restrict__ flagp,
                            int* __restrict__ cur, int* __restrict__ col, int E) {
    int e = blockIdx.x * blockDim.x + threadIdx.x;
    if (e >= E) return;
    int is64 = *flagp;
    int src = load_idx(ei, is64, e);
    int dst = load_idx(ei, is64, (long long)E + e);
    int pos = atomicAdd(&cur[dst], 1);
    col[pos] = src;
}

__global__ void deginv_kernel(const int* __restrict__ degi, float* __restrict__ dinv, int N) {
    int n = blockIdx.x * blockDim.x + threadIdx.x;
    if (n < N) dinv[n] = 1.0f / fmaxf((float)degi[n], 1.0f);
}

// wave per node: lane d sums dim d over the node's in-edges. 4x unrolled
// so 4 row loads are in flight per wave.
__global__ __launch_bounds__(256) void gather64_kernel(
    const float* __restrict__ h, const int* __restrict__ off, const int* __restrict__ endp,
    const int* __restrict__ col, float* __restrict__ agg, int N) {
    int wave = threadIdx.x >> 6;
    int lane = threadIdx.x & 63;
    int n = blockIdx.x * 4 + wave;
    if (n >= N) return;
    int e = off[n], end = endp[n];
    float acc = 0.f;
    for (; e + 4 <= end; e += 4) {
        int s0 = col[e], s1 = col[e + 1], s2 = col[e + 2], s3 = col[e + 3];
        float a0 = h[(size_t)s0 * 64 + lane];
        float a1 = h[(size_t)s1 * 64 + lane];
        float a2 = h[(size_t)s2 * 64 + lane];
        float a3 = h[(size_t)s3 * 64 + lane];
        acc += (a0 + a1) + (a2 + a3);
    }
    for (; e < end; ++e) acc += h[(size_t)col[e] * 64 + lane];
    agg[(size_t)n * 64 + lane] = acc;
}

// out[n,:] = act(h[n,:]@Ws + deginv[n]*agg[n,:]@Wn + b); out may alias agg
__global__ __launch_bounds__(256) void dense64_kernel(
    const float* __restrict__ h, const float* __restrict__ agg,
    const float* __restrict__ dinv, const float* __restrict__ Ws,
    const float* __restrict__ Wn, const float* __restrict__ b,
    float* __restrict__ out, int N, int do_relu) {
    __shared__ float sWs[64 * 64];
    __shared__ float sWn[64 * 64];
    for (int i = threadIdx.x; i < 64 * 64; i += 256) {
        sWs[i] = Ws[i];
        sWn[i] = Wn[i];
    }
    __syncthreads();
    int wave = threadIdx.x >> 6;
    int lane = threadIdx.x & 63;
    int n = blockIdx.x * 4 + wave;
    if (n >= N) return;
    const float* hrow = h + (size_t)n * 64;
    const float* arow = agg + (size_t)n * 64;
    float accs = 0.f, accn = 0.f;
#pragma unroll 8
    for (int k = 0; k < 64; ++k) {
        float hk = hrow[k];
        float ak = arow[k];
        accs = fmaf(hk, sWs[k * 64 + lane], accs);
        accn = fmaf(ak, sWn[k * 64 + lane], accn);
    }
    float v = accs + dinv[n] * accn + b[lane];
    if (do_relu) v = fmaxf(v, 0.f);
    out[(size_t)n * 64 + lane] = v;
}

// layer-4 pre-transform: s[n]=h[n,:]·Ws4, g[n]=h[n,:]·Wn4 (64->1)
__global__ __launch_bounds__(256) void layer4_pre_kernel(
    const float* __restrict__ h, const float* __restrict__ Ws,
    const float* __restrict__ Wn, float* __restrict__ s, float* __restrict__ g, int N) {
    int wave = threadIdx.x >> 6;
    int lane = threadIdx.x & 63;
    int n = blockIdx.x * 4 + wave;
    if (n >= N) return;
    float hv = h[(size_t)n * 64 + lane];
    float vs = hv * Ws[lane];
    float vn = hv * Wn[lane];
#pragma unroll
    for (int o = 32; o > 0; o >>= 1) {
        vs += __shfl_down(vs, o, 64);
        vn += __shfl_down(vn, o, 64);
    }
    if (lane == 0) {
        s[n] = vs;
        g[n] = vn;
    }
}

// thread per node: scalar CSR gather of g (400 KB, L2-resident) + sigmoid
__global__ void final_kernel(const float* __restrict__ s, const float* __restrict__ dinv,
                             const float* __restrict__ g, const int* __restrict__ off,
                             const int* __restrict__ endp, const int* __restrict__ col,
                             const float* __restrict__ b4, float* __restrict__ out, int N) {
    int n = blockIdx.x * blockDim.x + threadIdx.x;
    if (n >= N) return;
    float a = 0.f;
    int e = off[n], end = endp[n];
    for (; e < end; ++e) a += g[col[e]];
    float z = s[n] + dinv[n] * a + b4[0];
    out[n] = 1.0f / (1.0f + expf(-z));
}

static inline int cdiv(long long a, long long b) { return (int)((a + b - 1) / b); }

extern "C" void kernel_launch(void* const* d_in, const int* in_sizes, int n_in,
                              void* d_out, int out_size, void* d_ws, size_t ws_size,
                              hipStream_t stream) {
    const float* x   = (const float*)d_in[0];
    const void*  ei  = d_in[1];
    const float* Ws1 = (const float*)d_in[2];
    const float* Wn1 = (const float*)d_in[3];
    const float* b1  = (const float*)d_in[4];
    const float* Ws2 = (const float*)d_in[5];
    const float* Wn2 = (const float*)d_in[6];
    const float* b2  = (const float*)d_in[7];
    const float* Ws3 = (const float*)d_in[8];
    const float* Wn3 = (const float*)d_in[9];
    const float* b3  = (const float*)d_in[10];
    const float* Ws4 = (const float*)d_in[11];
    const float* Wn4 = (const float*)d_in[12];
    const float* b4  = (const float*)d_in[13];
    float* out = (float*)d_out;

    const int N = in_sizes[0] / 64;
    const int E = in_sizes[1] / 2;

    // workspace layout
    float* bufA = (float*)d_ws;                   // N*64
    float* bufB = bufA + (size_t)N * 64;          // N*64
    float* dinv = bufB + (size_t)N * 64;          // N
    float* sbuf = dinv + N;                       // N
    float* gbuf = sbuf + N;                       // N
    int*   degi = (int*)(gbuf + N);               // N
    int*   off  = degi + N;                       // N
    int*   curp = off + N;                        // N
    int*   col  = curp + N;                       // E
    int*   bsum = col + E;                        // 1024
    int*   flag = bsum + 1024;                    // 1

    const int BT = 256;
    const int gridN  = cdiv(N, BT);
    const int gridE  = cdiv(E, BT);
    const int gridNd = cdiv(N, 4);
    const int B      = cdiv(N, 1024);  // scan blocks (<=1024 for N<=1M)

    detect_idx_kernel<<<1, 1, 0, stream>>>((const int*)ei, flag);

    // ---- CSR build (once; edges are layer-invariant) ----
    zero_int_kernel<<<gridN, BT, 0, stream>>>(degi, N);
    hist_kernel<<<gridE, BT, 0, stream>>>(ei, flag, degi, E);
    scanA_kernel<<<B, 256, 0, stream>>>(degi, off, bsum, N);
    scanB_kernel<<<1, 1024, 0, stream>>>(bsum, B);
    scanC_kernel<<<gridN, BT, 0, stream>>>(off, bsum, N);
    copy_int_kernel<<<gridN, BT, 0, stream>>>(curp, off, N);
    fill_kernel<<<gridE, BT, 0, stream>>>(ei, flag, curp, col, E);  // curp -> row ends
    deginv_kernel<<<gridN, BT, 0, stream>>>(degi, dinv, N);

    // ---- layer 1: x -> bufA ----
    gather64_kernel<<<gridNd, BT, 0, stream>>>(x, off, curp, col, bufA, N);
    dense64_kernel<<<gridNd, BT, 0, stream>>>(x, bufA, dinv, Ws1, Wn1, b1, bufA, N, 1);

    // ---- layer 2: bufA -> bufB ----
    gather64_kernel<<<gridNd, BT, 0, stream>>>(bufA, off, curp, col, bufB, N);
    dense64_kernel<<<gridNd, BT, 0, stream>>>(bufA, bufB, dinv, Ws2, Wn2, b2, bufB, N, 1);

    // ---- layer 3: bufB -> bufA ----
    gather64_kernel<<<gridNd, BT, 0, stream>>>(bufB, off, curp, col, bufA, N);
    dense64_kernel<<<gridNd, BT, 0, stream>>>(bufB, bufA, dinv, Ws3, Wn3, b3, bufA, N, 1);

    // ---- layer 4 (64->1): pre-transform then scalar CSR gather + sigmoid ----
    layer4_pre_kernel<<<gridNd, BT, 0, stream>>>(bufA, Ws4, Wn4, sbuf, gbuf, N);
    final_kernel<<<gridN, BT, 0, stream>>>(sbuf, dinv, gbuf, off, curp, col, b4, out, N);
}

// Round 3
// 688.664 us; speedup vs baseline: 2.6439x; 1.3106x over previous
//
#include <hip/hip_runtime.h>
#include <hip/hip_bf16.h>
#include <math.h>

// ---------------------------------------------------------------------------
// ActorGNN: 4-layer GraphConv. R3:
//  - dense: weights-in-VGPR (col per lane), scalar-broadcast h/agg rows ->
//    pure v_fmac inner loop, no LDS (was LDS-issue-bound at 139us/layer)
//  - gather: float4 row loads, 4 edges per wave-instr, 2x unroll -> 8 rows
//    in flight per wave (was 1 dword/instr, latency-bound)
// ---------------------------------------------------------------------------

__device__ __forceinline__ int load_idx(const void* ei, int is64, long long pos) {
    if (is64) return (int)((const long long*)ei)[pos];
    return ((const int*)ei)[pos];
}

// int64 vs int32 edge_index detection (int64 values < 2^31 => odd words zero)
__global__ void detect_idx_kernel(const int* __restrict__ ei, int* __restrict__ flag) {
    int allz = 1;
    for (int i = 0; i < 32; ++i)
        if (ei[2 * i + 1] != 0) allz = 0;
    *flag = allz;
}

__global__ void zero_int_kernel(int* __restrict__ p, int n) {
    int i = blockIdx.x * blockDim.x + threadIdx.x;
    if (i < n) p[i] = 0;
}

__global__ void hist_kernel(const void* __restrict__ ei, const int* __restrict__ flagp,
                            int* __restrict__ degi, int E) {
    int e = blockIdx.x * blockDim.x + threadIdx.x;
    if (e >= E) return;
    int is64 = *flagp;
    int dst = load_idx(ei, is64, (long long)E + e);
    atomicAdd(&degi[dst], 1);
}

// exclusive scan over degi -> off, 1024 elems/block, block sums -> bsum
__global__ __launch_bounds__(256) void scanA_kernel(const int* __restrict__ degi,
                                                    int* __restrict__ off,
                                                    int* __restrict__ bsum, int N) {
    __shared__ int lds[256];
    int t = threadIdx.x;
    int base = blockIdx.x * 1024 + t * 4;
    int d[4];
#pragma unroll
    for (int i = 0; i < 4; ++i) d[i] = (base + i < N) ? degi[base + i] : 0;
    int s = d[0] + d[1] + d[2] + d[3];
    lds[t] = s;
    __syncthreads();
    for (int o = 1; o < 256; o <<= 1) {
        int v = (t >= o) ? lds[t - o] : 0;
        __syncthreads();
        lds[t] += v;
        __syncthreads();
    }
    int excl = lds[t] - s;
    if (t == 255) bsum[blockIdx.x] = lds[255];
    int p = excl;
#pragma unroll
    for (int i = 0; i < 4; ++i) {
        if (base + i < N) off[base + i] = p;
        p += d[i];
    }
}

__global__ __launch_bounds__(1024) void scanB_kernel(int* __restrict__ bsum, int B) {
    __shared__ int lds[1024];
    int t = threadIdx.x;
    int s = (t < B) ? bsum[t] : 0;
    lds[t] = s;
    __syncthreads();
    for (int o = 1; o < 1024; o <<= 1) {
        int v = (t >= o) ? lds[t - o] : 0;
        __syncthreads();
        lds[t] += v;
        __syncthreads();
    }
    if (t < B) bsum[t] = lds[t] - s;
}

__global__ void scanC_kernel(int* __restrict__ off, const int* __restrict__ bsum, int N) {
    int i = blockIdx.x * blockDim.x + threadIdx.x;
    if (i < N) off[i] += bsum[i >> 10];
}

__global__ void copy_int_kernel(int* __restrict__ dstp, const int* __restrict__ srcp, int n) {
    int i = blockIdx.x * blockDim.x + threadIdx.x;
    if (i < n) dstp[i] = srcp[i];
}

// fill CSR buckets; afterwards cur[n] == off[n] + deg[n] (used as `end`)
__global__ void fill_kernel(const void* __restrict__ ei, const int* __restrict__ flagp,
                            int* __restrict__ cur, int* __restrict__ col, int E) {
    int e = blockIdx.x * blockDim.x + threadIdx.x;
    if (e >= E) return;
    int is64 = *flagp;
    int src = load_idx(ei, is64, e);
    int dst = load_idx(ei, is64, (long long)E + e);
    int pos = atomicAdd(&cur[dst], 1);
    col[pos] = src;
}

__global__ void deginv_kernel(const int* __restrict__ degi, float* __restrict__ dinv, int N) {
    int n = blockIdx.x * blockDim.x + threadIdx.x;
    if (n < N) dinv[n] = 1.0f / fmaxf((float)degi[n], 1.0f);
}

// wave per node; lane = g*16 + t: edge-group g (0..3), dims t*4..t*4+3.
// One global_load_dwordx4 per wave fetches 4 full rows (1 KB).
__global__ __launch_bounds__(256) void gather64_kernel(
    const float* __restrict__ h, const int* __restrict__ off, const int* __restrict__ endp,
    const int* __restrict__ col, float* __restrict__ agg, int N) {
    int wave = threadIdx.x >> 6;
    int lane = threadIdx.x & 63;
    int g = lane >> 4;
    int t = lane & 15;
    int n = blockIdx.x * 4 + wave;
    if (n >= N) return;
    int e = off[n], end = endp[n];
    float4 acc = make_float4(0.f, 0.f, 0.f, 0.f);
    float4 acc2 = make_float4(0.f, 0.f, 0.f, 0.f);
    // main loop: 8 edges per iter, branch-free
    for (; e + 8 <= end; e += 8) {
        int s0 = col[e + g];
        int s1 = col[e + 4 + g];
        float4 v0 = *(const float4*)&h[(size_t)s0 * 64 + t * 4];
        float4 v1 = *(const float4*)&h[(size_t)s1 * 64 + t * 4];
        acc.x += v0.x; acc.y += v0.y; acc.z += v0.z; acc.w += v0.w;
        acc2.x += v1.x; acc2.y += v1.y; acc2.z += v1.z; acc2.w += v1.w;
    }
    // tail: predicated 4-at-a-time
    for (; e < end; e += 4) {
        if (e + g < end) {
            int s0 = col[e + g];
            float4 v0 = *(const float4*)&h[(size_t)s0 * 64 + t * 4];
            acc.x += v0.x; acc.y += v0.y; acc.z += v0.z; acc.w += v0.w;
        }
    }
    acc.x += acc2.x; acc.y += acc2.y; acc.z += acc2.z; acc.w += acc2.w;
    // combine the 4 edge-groups: butterfly over lane bits 4,5
#pragma unroll
    for (int m = 16; m <= 32; m <<= 1) {
        acc.x += __shfl_xor(acc.x, m, 64);
        acc.y += __shfl_xor(acc.y, m, 64);
        acc.z += __shfl_xor(acc.z, m, 64);
        acc.w += __shfl_xor(acc.w, m, 64);
    }
    if (g == 0) ((float4*)agg)[(size_t)n * 16 + t] = acc;
}

// out[n,:] = act(h[n,:]@Ws + dinv[n]*agg[n,:]@Wn + b); out may alias agg.
// Lane owns output dim `lane`: weight columns live in VGPRs, h/agg rows are
// scalar-broadcast loads (readfirstlane forces the SGPR/s_load path).
__global__ __launch_bounds__(256) void dense_reg_kernel(
    const float* __restrict__ h, const float* __restrict__ agg,
    const float* __restrict__ dinv, const float* __restrict__ Ws,
    const float* __restrict__ Wn, const float* __restrict__ b,
    float* __restrict__ out, int N, int do_relu) {
    int lane = threadIdx.x & 63;
    int wave_id = (blockIdx.x * blockDim.x + threadIdx.x) >> 6;
    int nwaves = (gridDim.x * blockDim.x) >> 6;
    float ws[64], wn[64];
#pragma unroll
    for (int k = 0; k < 64; ++k) {
        ws[k] = Ws[k * 64 + lane];
        wn[k] = Wn[k * 64 + lane];
    }
    float bl = b[lane];
    for (int n0 = wave_id; n0 < N; n0 += nwaves) {
        int n = __builtin_amdgcn_readfirstlane(n0);
        const float* hrow = h + (size_t)n * 64;
        const float* arow = agg + (size_t)n * 64;
        float di = dinv[n];
        float as0 = 0.f, as1 = 0.f, an0 = 0.f, an1 = 0.f;
#pragma unroll
        for (int k = 0; k < 64; k += 2) {
            as0 = fmaf(hrow[k], ws[k], as0);
            an0 = fmaf(arow[k], wn[k], an0);
            as1 = fmaf(hrow[k + 1], ws[k + 1], as1);
            an1 = fmaf(arow[k + 1], wn[k + 1], an1);
        }
        float v = (as0 + as1) + di * (an0 + an1) + bl;
        if (do_relu) v = fmaxf(v, 0.f);
        out[(size_t)n * 64 + lane] = v;
    }
}

// layer-4 pre-transform: s[n]=h[n,:]·Ws4, g[n]=h[n,:]·Wn4 (64->1)
__global__ __launch_bounds__(256) void layer4_pre_kernel(
    const float* __restrict__ h, const float* __restrict__ Ws,
    const float* __restrict__ Wn, float* __restrict__ s, float* __restrict__ g, int N) {
    int wave = threadIdx.x >> 6;
    int lane = threadIdx.x & 63;
    int n = blockIdx.x * 4 + wave;
    if (n >= N) return;
    float hv = h[(size_t)n * 64 + lane];
    float vs = hv * Ws[lane];
    float vn = hv * Wn[lane];
#pragma unroll
    for (int o = 32; o > 0; o >>= 1) {
        vs += __shfl_down(vs, o, 64);
        vn += __shfl_down(vn, o, 64);
    }
    if (lane == 0) {
        s[n] = vs;
        g[n] = vn;
    }
}

// thread per node: scalar CSR gather of g (400 KB, L2-resident) + sigmoid
__global__ void final_kernel(const float* __restrict__ s, const float* __restrict__ dinv,
                             const float* __restrict__ g, const int* __restrict__ off,
                             const int* __restrict__ endp, const int* __restrict__ col,
                             const float* __restrict__ b4, float* __restrict__ out, int N) {
    int n = blockIdx.x * blockDim.x + threadIdx.x;
    if (n >= N) return;
    float a = 0.f;
    int e = off[n], end = endp[n];
    for (; e < end; ++e) a += g[col[e]];
    float z = s[n] + dinv[n] * a + b4[0];
    out[n] = 1.0f / (1.0f + expf(-z));
}

static inline int cdiv(long long a, long long b) { return (int)((a + b - 1) / b); }

extern "C" void kernel_launch(void* const* d_in, const int* in_sizes, int n_in,
                              void* d_out, int out_size, void* d_ws, size_t ws_size,
                              hipStream_t stream) {
    const float* x   = (const float*)d_in[0];
    const void*  ei  = d_in[1];
    const float* Ws1 = (const float*)d_in[2];
    const float* Wn1 = (const float*)d_in[3];
    const float* b1  = (const float*)d_in[4];
    const float* Ws2 = (const float*)d_in[5];
    const float* Wn2 = (const float*)d_in[6];
    const float* b2  = (const float*)d_in[7];
    const float* Ws3 = (const float*)d_in[8];
    const float* Wn3 = (const float*)d_in[9];
    const float* b3  = (const float*)d_in[10];
    const float* Ws4 = (const float*)d_in[11];
    const float* Wn4 = (const float*)d_in[12];
    const float* b4  = (const float*)d_in[13];
    float* out = (float*)d_out;

    const int N = in_sizes[0] / 64;
    const int E = in_sizes[1] / 2;

    // workspace layout
    float* bufA = (float*)d_ws;                   // N*64
    float* bufB = bufA + (size_t)N * 64;          // N*64
    float* dinv = bufB + (size_t)N * 64;          // N
    float* sbuf = dinv + N;                       // N
    float* gbuf = sbuf + N;                       // N
    int*   degi = (int*)(gbuf + N);               // N
    int*   off  = degi + N;                       // N
    int*   curp = off + N;                        // N
    int*   col  = curp + N;                       // E
    int*   bsum = col + E;                        // 1024
    int*   flag = bsum + 1024;                    // 1

    const int BT = 256;
    const int gridN  = cdiv(N, BT);
    const int gridE  = cdiv(E, BT);
    const int gridNd = cdiv(N, 4);
    const int gridDense = 768;  // 3072 waves ~= 3 waves/SIMD at VGPR~140
    const int B      = cdiv(N, 1024);

    detect_idx_kernel<<<1, 1, 0, stream>>>((const int*)ei, flag);

    // ---- CSR build (once; edges are layer-invariant) ----
    zero_int_kernel<<<gridN, BT, 0, stream>>>(degi, N);
    hist_kernel<<<gridE, BT, 0, stream>>>(ei, flag, degi, E);
    scanA_kernel<<<B, 256, 0, stream>>>(degi, off, bsum, N);
    scanB_kernel<<<1, 1024, 0, stream>>>(bsum, B);
    scanC_kernel<<<gridN, BT, 0, stream>>>(off, bsum, N);
    copy_int_kernel<<<gridN, BT, 0, stream>>>(curp, off, N);
    fill_kernel<<<gridE, BT, 0, stream>>>(ei, flag, curp, col, E);
    deginv_kernel<<<gridN, BT, 0, stream>>>(degi, dinv, N);

    // ---- layer 1: x -> bufA ----
    gather64_kernel<<<gridNd, BT, 0, stream>>>(x, off, curp, col, bufA, N);
    dense_reg_kernel<<<gridDense, BT, 0, stream>>>(x, bufA, dinv, Ws1, Wn1, b1, bufA, N, 1);

    // ---- layer 2: bufA -> bufB ----
    gather64_kernel<<<gridNd, BT, 0, stream>>>(bufA, off, curp, col, bufB, N);
    dense_reg_kernel<<<gridDense, BT, 0, stream>>>(bufA, bufB, dinv, Ws2, Wn2, b2, bufB, N, 1);

    // ---- layer 3: bufB -> bufA ----
    gather64_kernel<<<gridNd, BT, 0, stream>>>(bufB, off, curp, col, bufA, N);
    dense_reg_kernel<<<gridDense, BT, 0, stream>>>(bufB, bufA, dinv, Ws3, Wn3, b3, bufA, N, 1);

    // ---- layer 4 (64->1): pre-transform then scalar CSR gather + sigmoid ----
    layer4_pre_kernel<<<gridNd, BT, 0, stream>>>(bufA, Ws4, Wn4, sbuf, gbuf, N);
    final_kernel<<<gridN, BT, 0, stream>>>(sbuf, dinv, gbuf, off, curp, col, b4, out, N);
}

// Round 4
// 641.886 us; speedup vs baseline: 2.8366x; 1.0729x over previous
//
#include <hip/hip_runtime.h>
#include <hip/hip_bf16.h>
#include <math.h>

// ---------------------------------------------------------------------------
// ActorGNN: 4-layer GraphConv. R4:
//  - fill: dst-range-partitioned (8 ranges, block = blockIdx&7) so scattered
//    col writes gain L2 line locality. R3's fill wrote 105MB (=E*64B: one
//    dirty line per 4B store); range version bounds it at 8 XCD * 6.4MB,
//    ~6.4MB if blockIdx%8 ~ XCD.
//  - index loads read only the low 4B of int64 entries.
//  - gather: 16 edges in flight per wave (4 float4 accumulator chains).
// ---------------------------------------------------------------------------

__device__ __forceinline__ int load_idx32(const int* __restrict__ ei32, int is64,
                                          long long pos) {
    return is64 ? ei32[2 * pos] : ei32[pos];
}

// int64 vs int32 edge_index detection (int64 values < 2^31 => odd words zero)
__global__ void detect_idx_kernel(const int* __restrict__ ei, int* __restrict__ flag) {
    int allz = 1;
    for (int i = 0; i < 32; ++i)
        if (ei[2 * i + 1] != 0) allz = 0;
    *flag = allz;
}

__global__ void zero_int_kernel(int* __restrict__ p, int n) {
    int i = blockIdx.x * blockDim.x + threadIdx.x;
    if (i < n) p[i] = 0;
}

__global__ void hist_kernel(const int* __restrict__ ei32, const int* __restrict__ flagp,
                            int* __restrict__ degi, int E) {
    int e = blockIdx.x * blockDim.x + threadIdx.x;
    if (e >= E) return;
    int is64 = *flagp;
    int dst = load_idx32(ei32, is64, (long long)E + e);
    atomicAdd(&degi[dst], 1);
}

// exclusive scan over degi -> off, 1024 elems/block, block sums -> bsum
__global__ __launch_bounds__(256) void scanA_kernel(const int* __restrict__ degi,
                                                    int* __restrict__ off,
                                                    int* __restrict__ bsum, int N) {
    __shared__ int lds[256];
    int t = threadIdx.x;
    int base = blockIdx.x * 1024 + t * 4;
    int d[4];
#pragma unroll
    for (int i = 0; i < 4; ++i) d[i] = (base + i < N) ? degi[base + i] : 0;
    int s = d[0] + d[1] + d[2] + d[3];
    lds[t] = s;
    __syncthreads();
    for (int o = 1; o < 256; o <<= 1) {
        int v = (t >= o) ? lds[t - o] : 0;
        __syncthreads();
        lds[t] += v;
        __syncthreads();
    }
    int excl = lds[t] - s;
    if (t == 255) bsum[blockIdx.x] = lds[255];
    int p = excl;
#pragma unroll
    for (int i = 0; i < 4; ++i) {
        if (base + i < N) off[base + i] = p;
        p += d[i];
    }
}

__global__ __launch_bounds__(1024) void scanB_kernel(int* __restrict__ bsum, int B) {
    __shared__ int lds[1024];
    int t = threadIdx.x;
    int s = (t < B) ? bsum[t] : 0;
    lds[t] = s;
    __syncthreads();
    for (int o = 1; o < 1024; o <<= 1) {
        int v = (t >= o) ? lds[t - o] : 0;
        __syncthreads();
        lds[t] += v;
        __syncthreads();
    }
    if (t < B) bsum[t] = lds[t] - s;
}

__global__ void scanC_kernel(int* __restrict__ off, const int* __restrict__ bsum, int N) {
    int i = blockIdx.x * blockDim.x + threadIdx.x;
    if (i < N) off[i] += bsum[i >> 10];
}

__global__ void copy_int_kernel(int* __restrict__ dstp, const int* __restrict__ srcp, int n) {
    int i = blockIdx.x * blockDim.x + threadIdx.x;
    if (i < n) dstp[i] = srcp[i];
}

// dst-range-partitioned CSR fill. Range r = blockIdx&7 handles dsts with
// (dst*41)>>19 == r (8 balanced ~12.8k-node ranges). col region per range is
// contiguous (~0.82MB) -> lines fill up in L2 before evicting.
// Afterwards cur[n] == off[n] + deg[n] (used as `end`).
__global__ __launch_bounds__(256) void fill_kernel(const int* __restrict__ ei32,
                                                   const int* __restrict__ flagp,
                                                   int* __restrict__ cur,
                                                   int* __restrict__ col, int E) {
    int r = blockIdx.x & 7;
    int chunk = blockIdx.x >> 3;
    int nchunks = gridDim.x >> 3;
    int is64 = *flagp;
    int stride = nchunks * 256;
    for (int e = chunk * 256 + threadIdx.x; e < E; e += stride) {
        int dst = load_idx32(ei32, is64, (long long)E + e);
        if ((int)(((unsigned)dst * 41u) >> 19) == r) {
            int src = load_idx32(ei32, is64, e);
            int pos = atomicAdd(&cur[dst], 1);
            col[pos] = src;
        }
    }
}

__global__ void deginv_kernel(const int* __restrict__ degi, float* __restrict__ dinv, int N) {
    int n = blockIdx.x * blockDim.x + threadIdx.x;
    if (n < N) dinv[n] = 1.0f / fmaxf((float)degi[n], 1.0f);
}

// wave per node; lane = g*16 + t: edge-group g (0..3), dims t*4..t*4+3.
// Main loop keeps 16 rows (4 dwordx4 per lane-group) in flight per wave.
__global__ __launch_bounds__(256) void gather64_kernel(
    const float* __restrict__ h, const int* __restrict__ off, const int* __restrict__ endp,
    const int* __restrict__ col, float* __restrict__ agg, int N) {
    int wave = threadIdx.x >> 6;
    int lane = threadIdx.x & 63;
    int g = lane >> 4;
    int t = lane & 15;
    int n = blockIdx.x * 4 + wave;
    if (n >= N) return;
    int e = off[n], end = endp[n];
    float4 a0 = make_float4(0.f, 0.f, 0.f, 0.f);
    float4 a1 = make_float4(0.f, 0.f, 0.f, 0.f);
    float4 a2 = make_float4(0.f, 0.f, 0.f, 0.f);
    float4 a3 = make_float4(0.f, 0.f, 0.f, 0.f);
    for (; e + 16 <= end; e += 16) {
        int s0 = col[e + g];
        int s1 = col[e + 4 + g];
        int s2 = col[e + 8 + g];
        int s3 = col[e + 12 + g];
        float4 v0 = *(const float4*)&h[(size_t)s0 * 64 + t * 4];
        float4 v1 = *(const float4*)&h[(size_t)s1 * 64 + t * 4];
        float4 v2 = *(const float4*)&h[(size_t)s2 * 64 + t * 4];
        float4 v3 = *(const float4*)&h[(size_t)s3 * 64 + t * 4];
        a0.x += v0.x; a0.y += v0.y; a0.z += v0.z; a0.w += v0.w;
        a1.x += v1.x; a1.y += v1.y; a1.z += v1.z; a1.w += v1.w;
        a2.x += v2.x; a2.y += v2.y; a2.z += v2.z; a2.w += v2.w;
        a3.x += v3.x; a3.y += v3.y; a3.z += v3.z; a3.w += v3.w;
    }
    for (; e + 8 <= end; e += 8) {
        int s0 = col[e + g];
        int s1 = col[e + 4 + g];
        float4 v0 = *(const float4*)&h[(size_t)s0 * 64 + t * 4];
        float4 v1 = *(const float4*)&h[(size_t)s1 * 64 + t * 4];
        a0.x += v0.x; a0.y += v0.y; a0.z += v0.z; a0.w += v0.w;
        a1.x += v1.x; a1.y += v1.y; a1.z += v1.z; a1.w += v1.w;
    }
    for (; e < end; e += 4) {
        if (e + g < end) {
            int s0 = col[e + g];
            float4 v0 = *(const float4*)&h[(size_t)s0 * 64 + t * 4];
            a2.x += v0.x; a2.y += v0.y; a2.z += v0.z; a2.w += v0.w;
        }
    }
    float4 acc;
    acc.x = (a0.x + a1.x) + (a2.x + a3.x);
    acc.y = (a0.y + a1.y) + (a2.y + a3.y);
    acc.z = (a0.z + a1.z) + (a2.z + a3.z);
    acc.w = (a0.w + a1.w) + (a2.w + a3.w);
#pragma unroll
    for (int m = 16; m <= 32; m <<= 1) {
        acc.x += __shfl_xor(acc.x, m, 64);
        acc.y += __shfl_xor(acc.y, m, 64);
        acc.z += __shfl_xor(acc.z, m, 64);
        acc.w += __shfl_xor(acc.w, m, 64);
    }
    if (g == 0) ((float4*)agg)[(size_t)n * 16 + t] = acc;
}

// out[n,:] = act(h[n,:]@Ws + dinv[n]*agg[n,:]@Wn + b); out may alias agg.
// Lane owns output dim `lane`: weight columns in VGPRs, h/agg rows are
// wave-uniform (scalar s_load path).
__global__ __launch_bounds__(256) void dense_reg_kernel(
    const float* __restrict__ h, const float* __restrict__ agg,
    const float* __restrict__ dinv, const float* __restrict__ Ws,
    const float* __restrict__ Wn, const float* __restrict__ b,
    float* __restrict__ out, int N, int do_relu) {
    int lane = threadIdx.x & 63;
    int wave_id = (blockIdx.x * blockDim.x + threadIdx.x) >> 6;
    int nwaves = (gridDim.x * blockDim.x) >> 6;
    float ws[64], wn[64];
#pragma unroll
    for (int k = 0; k < 64; ++k) {
        ws[k] = Ws[k * 64 + lane];
        wn[k] = Wn[k * 64 + lane];
    }
    float bl = b[lane];
    for (int n0 = wave_id; n0 < N; n0 += nwaves) {
        int n = __builtin_amdgcn_readfirstlane(n0);
        const float* hrow = h + (size_t)n * 64;
        const float* arow = agg + (size_t)n * 64;
        float di = dinv[n];
        float as0 = 0.f, as1 = 0.f, an0 = 0.f, an1 = 0.f;
#pragma unroll
        for (int k = 0; k < 64; k += 2) {
            as0 = fmaf(hrow[k], ws[k], as0);
            an0 = fmaf(arow[k], wn[k], an0);
            as1 = fmaf(hrow[k + 1], ws[k + 1], as1);
            an1 = fmaf(arow[k + 1], wn[k + 1], an1);
        }
        float v = (as0 + as1) + di * (an0 + an1) + bl;
        if (do_relu) v = fmaxf(v, 0.f);
        out[(size_t)n * 64 + lane] = v;
    }
}

// layer-4 pre-transform: s[n]=h[n,:]·Ws4, g[n]=h[n,:]·Wn4 (64->1)
__global__ __launch_bounds__(256) void layer4_pre_kernel(
    const float* __restrict__ h, const float* __restrict__ Ws,
    const float* __restrict__ Wn, float* __restrict__ s, float* __restrict__ g, int N) {
    int wave = threadIdx.x >> 6;
    int lane = threadIdx.x & 63;
    int n = blockIdx.x * 4 + wave;
    if (n >= N) return;
    float hv = h[(size_t)n * 64 + lane];
    float vs = hv * Ws[lane];
    float vn = hv * Wn[lane];
#pragma unroll
    for (int o = 32; o > 0; o >>= 1) {
        vs += __shfl_down(vs, o, 64);
        vn += __shfl_down(vn, o, 64);
    }
    if (lane == 0) {
        s[n] = vs;
        g[n] = vn;
    }
}

// thread per node: scalar CSR gather of g (400 KB, L2-resident) + sigmoid
__global__ void final_kernel(const float* __restrict__ s, const float* __restrict__ dinv,
                             const float* __restrict__ g, const int* __restrict__ off,
                             const int* __restrict__ endp, const int* __restrict__ col,
                             const float* __restrict__ b4, float* __restrict__ out, int N) {
    int n = blockIdx.x * blockDim.x + threadIdx.x;
    if (n >= N) return;
    float a = 0.f;
    int e = off[n], end = endp[n];
    for (; e < end; ++e) a += g[col[e]];
    float z = s[n] + dinv[n] * a + b4[0];
    out[n] = 1.0f / (1.0f + expf(-z));
}

static inline int cdiv(long long a, long long b) { return (int)((a + b - 1) / b); }

extern "C" void kernel_launch(void* const* d_in, const int* in_sizes, int n_in,
                              void* d_out, int out_size, void* d_ws, size_t ws_size,
                              hipStream_t stream) {
    const float* x   = (const float*)d_in[0];
    const int*   ei  = (const int*)d_in[1];
    const float* Ws1 = (const float*)d_in[2];
    const float* Wn1 = (const float*)d_in[3];
    const float* b1  = (const float*)d_in[4];
    const float* Ws2 = (const float*)d_in[5];
    const float* Wn2 = (const float*)d_in[6];
    const float* b2  = (const float*)d_in[7];
    const float* Ws3 = (const float*)d_in[8];
    const float* Wn3 = (const float*)d_in[9];
    const float* b3  = (const float*)d_in[10];
    const float* Ws4 = (const float*)d_in[11];
    const float* Wn4 = (const float*)d_in[12];
    const float* b4  = (const float*)d_in[13];
    float* out = (float*)d_out;

    const int N = in_sizes[0] / 64;
    const int E = in_sizes[1] / 2;

    // workspace layout
    float* bufA = (float*)d_ws;                   // N*64
    float* bufB = bufA + (size_t)N * 64;          // N*64
    float* dinv = bufB + (size_t)N * 64;          // N
    float* sbuf = dinv + N;                       // N
    float* gbuf = sbuf + N;                       // N
    int*   degi = (int*)(gbuf + N);               // N
    int*   off  = degi + N;                       // N
    int*   curp = off + N;                        // N
    int*   col  = curp + N;                       // E
    int*   bsum = col + E;                        // 1024
    int*   flag = bsum + 1024;                    // 1

    const int BT = 256;
    const int gridN  = cdiv(N, BT);
    const int gridE  = cdiv(E, BT);
    const int gridNd = cdiv(N, 4);
    const int gridDense = 768;
    const int gridFill  = 8 * 160;  // 8 dst-ranges x 160 chunks
    const int B      = cdiv(N, 1024);

    detect_idx_kernel<<<1, 1, 0, stream>>>(ei, flag);

    // ---- CSR build (once; edges are layer-invariant) ----
    zero_int_kernel<<<gridN, BT, 0, stream>>>(degi, N);
    hist_kernel<<<gridE, BT, 0, stream>>>(ei, flag, degi, E);
    scanA_kernel<<<B, 256, 0, stream>>>(degi, off, bsum, N);
    scanB_kernel<<<1, 1024, 0, stream>>>(bsum, B);
    scanC_kernel<<<gridN, BT, 0, stream>>>(off, bsum, N);
    copy_int_kernel<<<gridN, BT, 0, stream>>>(curp, off, N);
    fill_kernel<<<gridFill, BT, 0, stream>>>(ei, flag, curp, col, E);
    deginv_kernel<<<gridN, BT, 0, stream>>>(degi, dinv, N);

    // ---- layer 1: x -> bufA ----
    gather64_kernel<<<gridNd, BT, 0, stream>>>(x, off, curp, col, bufA, N);
    dense_reg_kernel<<<gridDense, BT, 0, stream>>>(x, bufA, dinv, Ws1, Wn1, b1, bufA, N, 1);

    // ---- layer 2: bufA -> bufB ----
    gather64_kernel<<<gridNd, BT, 0, stream>>>(bufA, off, curp, col, bufB, N);
    dense_reg_kernel<<<gridDense, BT, 0, stream>>>(bufA, bufB, dinv, Ws2, Wn2, b2, bufB, N, 1);

    // ---- layer 3: bufB -> bufA ----
    gather64_kernel<<<gridNd, BT, 0, stream>>>(bufB, off, curp, col, bufA, N);
    dense_reg_kernel<<<gridDense, BT, 0, stream>>>(bufB, bufA, dinv, Ws3, Wn3, b3, bufA, N, 1);

    // ---- layer 4 (64->1): pre-transform then scalar CSR gather + sigmoid ----
    layer4_pre_kernel<<<gridNd, BT, 0, stream>>>(bufA, Ws4, Wn4, sbuf, gbuf, N);
    final_kernel<<<gridN, BT, 0, stream>>>(sbuf, dinv, gbuf, off, curp, col, b4, out, N);
}